// Round 10
// baseline (57570.764 us; speedup 1.0000x reference)
//
#include <hip/hip_runtime.h>
#include <math.h>

#define B64   64
#define TT    512
#define U400  400
#define G1600 1600
#define NBPL  50            // blocks per layer per role
#define UPB   8             // units per block (32 gate-columns)
#define NCOL  (4 * UPB)
#define NW    8             // waves per block
#define NTHR  512
#define NBWH  (3 * NBPL)    // 150 Wh blocks
#define NBWX  (2 * NBPL)    // 100 Wx blocks (layers 1,2)
#define NBLK  (NBWH + NBWX + 1) // 251 (<=256: coop-safe at 1 block/CU)

// ---- device-coherent access helpers: bypass L1/L2, served at coherence point ----
__device__ __forceinline__ float ldg_c(const float* p) {
  return __hip_atomic_load(p, __ATOMIC_RELAXED, __HIP_MEMORY_SCOPE_AGENT);
}
__device__ __forceinline__ void stg_c(float* p, float v) {
  __hip_atomic_store(p, v, __ATOMIC_RELAXED, __HIP_MEMORY_SCOPE_AGENT);
}
__device__ __forceinline__ int adl(const unsigned* p) {
  return (int)__hip_atomic_load(p, __ATOMIC_RELAXED, __HIP_MEMORY_SCOPE_AGENT);
}

// x [64][512][3] -> xT [512][3][64]
__global__ void xpose_x_k(const float* __restrict__ x, float* __restrict__ xT) {
  int idx = blockIdx.x * 256 + threadIdx.x;
  if (idx < B64 * TT * 3) {
    int d = idx % 3;
    int t = (idx / 3) % TT;
    int b = idx / (3 * TT);
    xT[(t * 3 + d) * B64 + b] = x[idx];
  }
}

// generic tiled transpose: in R x C -> out C x R
__global__ void transpose_k(const float* __restrict__ in, float* __restrict__ out,
                            int R, int C) {
  __shared__ float tile[32][33];
  int bx = blockIdx.x * 32, by = blockIdx.y * 32;
  int tx = threadIdx.x, ty = threadIdx.y; // block (32,8)
  #pragma unroll
  for (int i = ty; i < 32; i += 8) {
    int r = by + i, c = bx + tx;
    if (r < R && c < C) tile[i][tx] = in[(size_t)r * C + c];
  }
  __syncthreads();
  #pragma unroll
  for (int i = ty; i < 32; i += 8) {
    int r = bx + i, c = by + tx;
    if (r < C && c < R) out[(size_t)r * R + c] = tile[tx][i];
  }
}

// K-slice GEMM over NQ quads. Activations: 4 independent coherent loads per
// quad, unroll 4 => ~16 in flight. Weights: float4 broadcast loads feeding
// 4 FMAs each. acc stays in VGPRs (array ref; grid<=256 so VGPRs are uncapped).
template <int NQ>
__device__ __forceinline__ void gemm_q(const float* __restrict__ aslab,
                                       int lane,
                                       const float* __restrict__ wg0,
                                       const float* __restrict__ wg1,
                                       const float* __restrict__ wg2,
                                       const float* __restrict__ wg3,
                                       float (&acc)[NCOL]) {
  #pragma unroll 4
  for (int q = 0; q < NQ; ++q) {
    const float a0 = ldg_c(aslab + (size_t)(4 * q + 0) * B64 + lane);
    const float a1 = ldg_c(aslab + (size_t)(4 * q + 1) * B64 + lane);
    const float a2 = ldg_c(aslab + (size_t)(4 * q + 2) * B64 + lane);
    const float a3 = ldg_c(aslab + (size_t)(4 * q + 3) * B64 + lane);
    #pragma unroll
    for (int uu = 0; uu < UPB; ++uu) {
      const float4 w = *reinterpret_cast<const float4*>(wg0 + uu * U400 + 4 * q);
      acc[0 * UPB + uu] += a0 * w.x + a1 * w.y + a2 * w.z + a3 * w.w;
    }
    #pragma unroll
    for (int uu = 0; uu < UPB; ++uu) {
      const float4 w = *reinterpret_cast<const float4*>(wg1 + uu * U400 + 4 * q);
      acc[1 * UPB + uu] += a0 * w.x + a1 * w.y + a2 * w.z + a3 * w.w;
    }
    #pragma unroll
    for (int uu = 0; uu < UPB; ++uu) {
      const float4 w = *reinterpret_cast<const float4*>(wg2 + uu * U400 + 4 * q);
      acc[2 * UPB + uu] += a0 * w.x + a1 * w.y + a2 * w.z + a3 * w.w;
    }
    #pragma unroll
    for (int uu = 0; uu < UPB; ++uu) {
      const float4 w = *reinterpret_cast<const float4*>(wg3 + uu * U400 + 4 * q);
      acc[3 * UPB + uu] += a0 * w.x + a1 * w.y + a2 * w.z + a3 * w.w;
    }
  }
}

struct ScanP {
  const float *xT0, *Wx0;
  const float *WxT1, *WxT2;
  const float *WhT0, *WhT1, *WhT2;
  const float *b0, *b1, *b2;
  const float *pi0, *pi1, *pi2;
  const float *pf0, *pf1, *pf2;
  const float *po0, *po1, *po2;
  const float *Wd, *bd;
  float *h0r, *h1r, *h2r;  // 8-slot h rings [8][400][64]
  float *zx1, *zx2;        // 8-slot zx rings [8][1600][64]
  float *outp;             // d_out [64][512][3]
  unsigned *syn;           // counters, 128B-strided
};

#define CNT(l)  (p.syn + (l) * 32)         // Wh steps published, layer l
#define XCNT(l) (p.syn + (3 + (l)) * 32)   // Wx steps published (l=1,2)
#define DCNT    (p.syn + 6 * 32)           // dense steps published
#define AAC(l)  (p.syn + (7 + (l)) * 32)   // Wh arrive accumulator
#define XAC(l)  (p.syn + (10 + (l)) * 32)  // Wx arrive accumulator (l=1,2)

// Persistent LSTM scan + fused dense head, Wx off the critical path.
// Blocks 0..149: Wh (layer bid/50). 150..249: Wx (layer 1 + (bid-150)/50).
// Block 250: dense head (reads h2 ring, writes d_out directly).
__launch_bounds__(NTHR)
__global__ void lstm_scan_k(ScanP p) {
  const int bid  = blockIdx.x;
  const int lane = threadIdx.x & 63;
  const int kq   = __builtin_amdgcn_readfirstlane(threadIdx.x >> 6); // 0..7
  const int k0   = (kq < 4) ? kq * 52 : 208 + (kq - 4) * 48;  // mult of 4

  __shared__ float zs[NW][NCOL][B64];   // 64 KB partials

  // ================= dense head block =================
  if (bid == NBWH + NBWX) {
    for (int t = 0; t < TT; ++t) {
      if (threadIdx.x == 0)
        while (adl(CNT(2)) < t + 1) __builtin_amdgcn_s_sleep(1);
      __syncthreads();
      {
        const float* hrow = p.h2r + (size_t)(t & 7) * (U400 * B64) +
                            (size_t)k0 * B64;
        const int klen = (kq < 4) ? 52 : 48;
        float a0 = 0.f, a1 = 0.f, a2 = 0.f;
        for (int kk = 0; kk < klen; ++kk) {
          float h = ldg_c(hrow + (size_t)kk * B64 + lane);
          a0 += h * p.Wd[(k0 + kk) * 3 + 0];
          a1 += h * p.Wd[(k0 + kk) * 3 + 1];
          a2 += h * p.Wd[(k0 + kk) * 3 + 2];
        }
        zs[kq][0][lane] = a0;
        zs[kq][1][lane] = a1;
        zs[kq][2][lane] = a2;
      }
      __syncthreads();
      if (threadIdx.x < 3 * B64) {
        const int f = threadIdx.x >> 6;
        float s = p.bd[f];
        #pragma unroll
        for (int w = 0; w < NW; ++w) s += zs[w][f][lane];
        p.outp[((size_t)lane * TT + t) * 3 + f] = s;
      }
      __syncthreads();
      if (threadIdx.x == 0)
        __hip_atomic_store(DCNT, (unsigned)(t + 1), __ATOMIC_RELAXED,
                           __HIP_MEMORY_SCOPE_AGENT);
    }
    return;
  }

  // ================= Wh / Wx blocks =================
  const bool wh = (bid < NBWH);
  const int l   = wh ? (bid / NBPL) : (1 + (bid - NBWH) / NBPL);
  const int u0  = (wh ? (bid % NBPL) : ((bid - NBWH) % NBPL)) * UPB;

  const float* bias = (l == 0) ? p.b0  : (l == 1 ? p.b1  : p.b2);
  const float* pi   = (l == 0) ? p.pi0 : (l == 1 ? p.pi1 : p.pi2);
  const float* pf   = (l == 0) ? p.pf0 : (l == 1 ? p.pf1 : p.pf2);
  const float* po   = (l == 0) ? p.po0 : (l == 1 ? p.po1 : p.po2);
  const float* prevb = (l == 1) ? p.h0r : p.h1r;   // Wx input ring
  float* ownb = (l == 0) ? p.h0r : (l == 1 ? p.h1r : p.h2r);
  float* zxl  = (l == 1) ? p.zx1 : p.zx2;

  const float* wb;
  if (wh) wb = (l == 0) ? p.WhT0 : (l == 1 ? p.WhT1 : p.WhT2);
  else    wb = (l == 1) ? p.WxT1 : p.WxT2;

  const float* wg0 = wb + (size_t)(0 * U400 + u0) * U400 + k0;
  const float* wg1 = wb + (size_t)(1 * U400 + u0) * U400 + k0;
  const float* wg2 = wb + (size_t)(2 * U400 + u0) * U400 + k0;
  const float* wg3 = wb + (size_t)(3 * U400 + u0) * U400 + k0;

  float creg = 0.f;

  for (int t = 0; t < TT; ++t) {
    // ---- waits (thread 0) ----
    if (threadIdx.x == 0) {
      if (wh) {
        while (adl(CNT(l)) < t) __builtin_amdgcn_s_sleep(1);
        if (l > 0)
          while (adl(XCNT(l)) < t + 1) __builtin_amdgcn_s_sleep(1);
        if (l < 2) {  // own-ring slot free: Wx(l+1) consumed h_l[t-8]
          while (adl(XCNT(l + 1)) < t - 7) __builtin_amdgcn_s_sleep(1);
        } else {      // h2 ring slot free: dense consumed h2[t-8]
          while (adl(DCNT) < t - 7) __builtin_amdgcn_s_sleep(1);
        }
      } else {
        while (adl(CNT(l - 1)) < t + 1) __builtin_amdgcn_s_sleep(1);
        while (adl(CNT(l)) < t - 7) __builtin_amdgcn_s_sleep(1);  // zx slot free
      }
    }
    __syncthreads();

    // ---- zx prefetch for Wh pointwise (arrives under the GEMM) ----
    float zq0 = 0.f, zq1 = 0.f, zq2 = 0.f, zq3 = 0.f;
    if (wh && l > 0) {
      const int uu = threadIdx.x >> 6;
      const float* zp = zxl + ((size_t)(t & 7) * G1600 + u0 + uu) * B64 + lane;
      zq0 = ldg_c(zp + (size_t)(0 * U400) * B64);
      zq1 = ldg_c(zp + (size_t)(1 * U400) * B64);
      zq2 = ldg_c(zp + (size_t)(2 * U400) * B64);
      zq3 = ldg_c(zp + (size_t)(3 * U400) * B64);
    }

    // ---- GEMM phase ----
    {
      float acc[NCOL];
      #pragma unroll
      for (int c = 0; c < NCOL; ++c) acc[c] = 0.f;

      if (!(wh && t == 0)) {
        const float* aslab = wh
            ? ownb  + (size_t)((t - 1) & 7) * (U400 * B64) + (size_t)k0 * B64
            : prevb + (size_t)(t & 7)       * (U400 * B64) + (size_t)k0 * B64;
        if (kq < 4) gemm_q<13>(aslab, lane, wg0, wg1, wg2, wg3, acc);
        else        gemm_q<12>(aslab, lane, wg0, wg1, wg2, wg3, acc);
      }
      #pragma unroll
      for (int c = 0; c < NCOL; ++c) zs[kq][c][lane] = acc[c];
    }
    __syncthreads();

    // ---- reduce + emit (all 512 threads: uu = 0..7) ----
    {
      const int uu = threadIdx.x >> 6;
      const int b  = lane;
      const int u  = u0 + uu;
      float z0 = 0.f, z1 = 0.f, z2 = 0.f, z3 = 0.f;
      #pragma unroll
      for (int w = 0; w < NW; ++w) {
        z0 += zs[w][0 * UPB + uu][b];
        z1 += zs[w][1 * UPB + uu][b];
        z2 += zs[w][2 * UPB + uu][b];
        z3 += zs[w][3 * UPB + uu][b];
      }
      if (wh) {
        z0 += bias[0 * U400 + u] + zq0;
        z1 += bias[1 * U400 + u] + zq1;
        z2 += bias[2 * U400 + u] + zq2;
        z3 += bias[3 * U400 + u] + zq3;
        if (l == 0) {
          #pragma unroll
          for (int dd = 0; dd < 3; ++dd) {
            float xv = p.xT0[(t * 3 + dd) * B64 + b];
            z0 += xv * p.Wx0[dd * G1600 + 0 * U400 + u];
            z1 += xv * p.Wx0[dd * G1600 + 1 * U400 + u];
            z2 += xv * p.Wx0[dd * G1600 + 2 * U400 + u];
            z3 += xv * p.Wx0[dd * G1600 + 3 * U400 + u];
          }
        }
        float cp = creg;
        float ig = 1.f / (1.f + expf(-(z0 + pi[u] * cp)));
        float fg = 1.f / (1.f + expf(-(z1 + pf[u] * cp)));
        float gg = tanhf(z2);
        float cn = fg * cp + ig * gg;
        float og = 1.f / (1.f + expf(-(z3 + po[u] * cn)));
        creg = cn;
        float h = og * tanhf(cn);
        stg_c(&ownb[(size_t)(t & 7) * (U400 * B64) + (size_t)u * B64 + b], h);
      } else {
        float* zp = zxl + ((size_t)(t & 7) * G1600 + u0 + uu) * B64 + b;
        stg_c(zp + (size_t)(0 * U400) * B64, z0);
        stg_c(zp + (size_t)(1 * U400) * B64, z1);
        stg_c(zp + (size_t)(2 * U400) * B64, z2);
        stg_c(zp + (size_t)(3 * U400) * B64, z3);
      }
    }

    // drain: all coherent stores acked before the arrive RMW below
    __syncthreads();

    // ---- arrive (monotone accumulators; no resets) ----
    if (threadIdx.x == 0) {
      unsigned* ac = wh ? AAC(l) : XAC(l);
      unsigned old = __hip_atomic_fetch_add(ac, 1u, __ATOMIC_RELAXED,
                                            __HIP_MEMORY_SCOPE_AGENT);
      if (old == (unsigned)((t + 1) * NBPL - 1)) {
        unsigned* c = wh ? CNT(l) : XCNT(l);
        __hip_atomic_store(c, (unsigned)(t + 1), __ATOMIC_RELAXED,
                           __HIP_MEMORY_SCOPE_AGENT);
      }
    }
  }
}

extern "C" void kernel_launch(void* const* d_in, const int* in_sizes, int n_in,
                              void* d_out, int out_size, void* d_ws, size_t ws_size,
                              hipStream_t stream) {
  const float* x   = (const float*)d_in[0];
  const float* Wx0 = (const float*)d_in[1];
  const float* Wh0 = (const float*)d_in[2];
  const float* pi0 = (const float*)d_in[3];
  const float* pf0 = (const float*)d_in[4];
  const float* po0 = (const float*)d_in[5];
  const float* b0  = (const float*)d_in[6];
  const float* Wx1 = (const float*)d_in[7];
  const float* Wh1 = (const float*)d_in[8];
  const float* pi1 = (const float*)d_in[9];
  const float* pf1 = (const float*)d_in[10];
  const float* po1 = (const float*)d_in[11];
  const float* b1  = (const float*)d_in[12];
  const float* Wx2 = (const float*)d_in[13];
  const float* Wh2 = (const float*)d_in[14];
  const float* pi2 = (const float*)d_in[15];
  const float* pf2 = (const float*)d_in[16];
  const float* po2 = (const float*)d_in[17];
  const float* b2  = (const float*)d_in[18];
  const float* Wd  = (const float*)d_in[19];
  const float* bd  = (const float*)d_in[20];

  float* ws   = (float*)d_ws;
  float* xT0  = ws;                  // 98304
  float* WhT0 = xT0  + 98304;        // 640000 each
  float* WhT1 = WhT0 + 640000;
  float* WhT2 = WhT1 + 640000;
  float* WxT1 = WhT2 + 640000;
  float* WxT2 = WxT1 + 640000;
  float* h0r  = WxT2 + 640000;       // 8*400*64 = 204800 each
  float* h1r  = h0r  + 204800;
  float* h2r  = h1r  + 204800;
  float* zx1  = h2r  + 204800;       // 8*1600*64 = 819200 each
  float* zx2  = zx1  + 819200;
  unsigned* syn = (unsigned*)(zx2 + 819200);  // 13 lines x 128B
  // total ~22.2 MB (proven-safe: rounds 2-7 used 67.3 MB)

  hipMemsetAsync(syn, 0, 13 * 128, stream);

  hipLaunchKernelGGL(xpose_x_k, dim3(384), dim3(256), 0, stream, x, xT0);

  dim3 tb(32, 8);
  dim3 tg((G1600 + 31) / 32, (U400 + 31) / 32);
  hipLaunchKernelGGL(transpose_k, tg, tb, 0, stream, Wh0, WhT0, U400, G1600);
  hipLaunchKernelGGL(transpose_k, tg, tb, 0, stream, Wh1, WhT1, U400, G1600);
  hipLaunchKernelGGL(transpose_k, tg, tb, 0, stream, Wh2, WhT2, U400, G1600);
  hipLaunchKernelGGL(transpose_k, tg, tb, 0, stream, Wx1, WxT1, U400, G1600);
  hipLaunchKernelGGL(transpose_k, tg, tb, 0, stream, Wx2, WxT2, U400, G1600);

  ScanP hp;
  hp.xT0 = xT0;  hp.Wx0 = Wx0;
  hp.WxT1 = WxT1; hp.WxT2 = WxT2;
  hp.WhT0 = WhT0; hp.WhT1 = WhT1; hp.WhT2 = WhT2;
  hp.b0 = b0; hp.b1 = b1; hp.b2 = b2;
  hp.pi0 = pi0; hp.pi1 = pi1; hp.pi2 = pi2;
  hp.pf0 = pf0; hp.pf1 = pf1; hp.pf2 = pf2;
  hp.po0 = po0; hp.po1 = po1; hp.po2 = po2;
  hp.Wd = Wd; hp.bd = bd;
  hp.h0r = h0r; hp.h1r = h1r; hp.h2r = h2r;
  hp.zx1 = zx1; hp.zx2 = zx2;
  hp.outp = (float*)d_out;
  hp.syn = syn;

  void* args[] = { &hp };
  hipLaunchCooperativeKernel((void*)lstm_scan_k, dim3(NBLK), dim3(NTHR),
                             args, 0, stream);
}

// Round 11
// 34527.161 us; speedup vs baseline: 1.6674x; 1.6674x over previous
//
#include <hip/hip_runtime.h>
#include <math.h>

#define B64   64
#define TT    512
#define U400  400
#define G1600 1600
#define NBPL  80            // blocks per layer
#define UPB   5             // units per block (20 gate-columns)
#define NCOL  (4 * UPB)
#define NW    8             // waves per block
#define NTHR  512
#define NBLK  (3 * NBPL)    // 240 <= 256 CUs -> 1 block/CU, VGPRs uncapped

// ---- device-coherent access helpers: bypass L1/L2, served at coherence point ----
__device__ __forceinline__ float ldg_c(const float* p) {
  return __hip_atomic_load(p, __ATOMIC_RELAXED, __HIP_MEMORY_SCOPE_AGENT);
}
__device__ __forceinline__ void stg_c(float* p, float v) {
  __hip_atomic_store(p, v, __ATOMIC_RELAXED, __HIP_MEMORY_SCOPE_AGENT);
}
__device__ __forceinline__ int adl(const unsigned* p) {
  return (int)__hip_atomic_load(p, __ATOMIC_RELAXED, __HIP_MEMORY_SCOPE_AGENT);
}

// x [64][512][3] -> xT [512][3][64]
__global__ void xpose_x_k(const float* __restrict__ x, float* __restrict__ xT) {
  int idx = blockIdx.x * 256 + threadIdx.x;
  if (idx < B64 * TT * 3) {
    int d = idx % 3;
    int t = (idx / 3) % TT;
    int b = idx / (3 * TT);
    xT[(t * 3 + d) * B64 + b] = x[idx];
  }
}

// generic tiled transpose: in R x C -> out C x R
__global__ void transpose_k(const float* __restrict__ in, float* __restrict__ out,
                            int R, int C) {
  __shared__ float tile[32][33];
  int bx = blockIdx.x * 32, by = blockIdx.y * 32;
  int tx = threadIdx.x, ty = threadIdx.y; // block (32,8)
  #pragma unroll
  for (int i = ty; i < 32; i += 8) {
    int r = by + i, c = bx + tx;
    if (r < R && c < C) tile[i][tx] = in[(size_t)r * C + c];
  }
  __syncthreads();
  #pragma unroll
  for (int i = ty; i < 32; i += 8) {
    int r = bx + i, c = by + tx;
    if (r < C && c < R) out[(size_t)r * R + c] = tile[tx][i];
  }
}

// ---- software-pipelined GEMM pieces (all indices compile-time) ----
template <int N>
__device__ __forceinline__ void issue_n(const float* __restrict__ base, int lane,
                                        float (&buf)[28]) {
  #pragma unroll
  for (int i = 0; i < N; ++i)
    buf[i] = ldg_c(base + (size_t)i * B64 + lane);
}

// consume Q quads from buf; weights via float4 broadcast loads (L1-resident)
template <int Q>
__device__ __forceinline__ void consume_q(const float (&buf)[28], int koff,
                                          const float* __restrict__ wg0,
                                          const float* __restrict__ wg1,
                                          const float* __restrict__ wg2,
                                          const float* __restrict__ wg3,
                                          float (&acc)[NCOL]) {
  #pragma unroll
  for (int q = 0; q < Q; ++q) {
    const float a0 = buf[4 * q + 0];
    const float a1 = buf[4 * q + 1];
    const float a2 = buf[4 * q + 2];
    const float a3 = buf[4 * q + 3];
    const int k = koff + 4 * q;
    #pragma unroll
    for (int uu = 0; uu < UPB; ++uu) {
      const float4 w = *reinterpret_cast<const float4*>(wg0 + uu * U400 + k);
      acc[0 * UPB + uu] += a0 * w.x + a1 * w.y + a2 * w.z + a3 * w.w;
    }
    #pragma unroll
    for (int uu = 0; uu < UPB; ++uu) {
      const float4 w = *reinterpret_cast<const float4*>(wg1 + uu * U400 + k);
      acc[1 * UPB + uu] += a0 * w.x + a1 * w.y + a2 * w.z + a3 * w.w;
    }
    #pragma unroll
    for (int uu = 0; uu < UPB; ++uu) {
      const float4 w = *reinterpret_cast<const float4*>(wg2 + uu * U400 + k);
      acc[2 * UPB + uu] += a0 * w.x + a1 * w.y + a2 * w.z + a3 * w.w;
    }
    #pragma unroll
    for (int uu = 0; uu < UPB; ++uu) {
      const float4 w = *reinterpret_cast<const float4*>(wg3 + uu * U400 + k);
      acc[3 * UPB + uu] += a0 * w.x + a1 * w.y + a2 * w.z + a3 * w.w;
    }
  }
}

struct ScanP {
  const float *xT0, *Wx0;
  const float *WxT1, *WxT2;
  const float *WhT0, *WhT1, *WhT2;
  const float *b0, *b1, *b2;
  const float *pi0, *pi1, *pi2;
  const float *pf0, *pf1, *pf2;
  const float *po0, *po1, *po2;
  float *h0r, *h1r;   // 8-slot h rings [8][400][64]
  float *h2;          // full [512][400][64]
  unsigned *syn;      // counters, 128B-strided
};

#define CNT(l)  (p.syn + (l) * 32)        // published step count, layer l
#define AAC(l)  (p.syn + (3 + (l)) * 32)  // arrive accumulator, layer l

// Persistent LSTM scan (round-4 proven skeleton + pipelined GEMM).
// grid = 240 blocks (80/layer), block = 512 threads (8 waves).
// l=0: 8 waves split own-h K=400 as {52x4,48x4}; x-term in pointwise.
// l>0: waves 0-3 = Wx on prev-h (k0=kq*100), waves 4-7 = Wh on own h.
__launch_bounds__(NTHR, 1)
__global__ void lstm_scan_k(ScanP p) {
  const int l    = blockIdx.x / NBPL;
  const int u0   = (blockIdx.x % NBPL) * UPB;
  const int lane = threadIdx.x & 63;
  const int kq   = __builtin_amdgcn_readfirstlane(threadIdx.x >> 6); // 0..7

  __shared__ float zs[NW][NCOL][B64];   // 40 KB partials

  const float* WhT  = (l == 0) ? p.WhT0 : (l == 1 ? p.WhT1 : p.WhT2);
  const float* WxT  = (l == 1) ? p.WxT1 : p.WxT2;      // unused for l==0
  const float* bias = (l == 0) ? p.b0  : (l == 1 ? p.b1  : p.b2);
  const float* pi   = (l == 0) ? p.pi0 : (l == 1 ? p.pi1 : p.pi2);
  const float* pf   = (l == 0) ? p.pf0 : (l == 1 ? p.pf1 : p.pf2);
  const float* po   = (l == 0) ? p.po0 : (l == 1 ? p.po1 : p.po2);
  const float* prevb = (l == 1) ? p.h0r : p.h1r;
  float* ownb = (l == 0) ? p.h0r : (l == 1 ? p.h1r : p.h2);
  const int ownmask = (l == 2) ? (TT - 1) : 7;

  // wave's K-slice (wave-uniform; k0 multiple of 4)
  const float* wb; int k0, isH;
  if (l == 0) {
    wb = WhT; isH = 1;
    k0 = (kq < 4) ? kq * 52 : 208 + (kq - 4) * 48;
  } else if (kq < 4) {
    wb = WxT; isH = 0; k0 = kq * 100;
  } else {
    wb = WhT; isH = 1; k0 = (kq - 4) * 100;
  }

  const float* wg0 = wb + (size_t)(0 * U400 + u0) * U400 + k0;
  const float* wg1 = wb + (size_t)(1 * U400 + u0) * U400 + k0;
  const float* wg2 = wb + (size_t)(2 * U400 + u0) * U400 + k0;
  const float* wg3 = wb + (size_t)(3 * U400 + u0) * U400 + k0;

  float creg = 0.f;

  for (int t = 0; t < TT; ++t) {
    // ---- wait phase (thread 0 spins on device-coherent counters) ----
    if (threadIdx.x == 0) {
      while (adl(CNT(l)) < t) __builtin_amdgcn_s_sleep(1);
      if (l > 0)
        while (adl(CNT(l - 1)) < t + 1) __builtin_amdgcn_s_sleep(1);
      if (l < 2)
        while (adl(CNT(l + 1)) < t - 7) __builtin_amdgcn_s_sleep(1);
    }
    __syncthreads();

    // ---- GEMM phase: two-buffer pipelined chunks, ~48 loads in flight ----
    {
      float acc[NCOL];
      #pragma unroll
      for (int c = 0; c < NCOL; ++c) acc[c] = 0.f;

      if (!(isH && t == 0)) {
        const float* aslab = isH
            ? ownb  + (size_t)((t - 1) & ownmask) * (U400 * B64) + (size_t)k0 * B64
            : prevb + (size_t)(t & 7)             * (U400 * B64) + (size_t)k0 * B64;
        float aA[28], aB[28];
        if (l != 0) {                 // slice 100 = {24,24,24,28}
          issue_n<24>(aslab, lane, aA);
          issue_n<24>(aslab + 24 * B64, lane, aB);
          consume_q<6>(aA, 0,  wg0, wg1, wg2, wg3, acc);
          issue_n<24>(aslab + 48 * B64, lane, aA);
          consume_q<6>(aB, 24, wg0, wg1, wg2, wg3, acc);
          issue_n<28>(aslab + 72 * B64, lane, aB);
          consume_q<6>(aA, 48, wg0, wg1, wg2, wg3, acc);
          consume_q<7>(aB, 72, wg0, wg1, wg2, wg3, acc);
        } else if (kq < 4) {          // slice 52 = {24,28}
          issue_n<24>(aslab, lane, aA);
          issue_n<28>(aslab + 24 * B64, lane, aB);
          consume_q<6>(aA, 0,  wg0, wg1, wg2, wg3, acc);
          consume_q<7>(aB, 24, wg0, wg1, wg2, wg3, acc);
        } else {                      // slice 48 = {24,24}
          issue_n<24>(aslab, lane, aA);
          issue_n<24>(aslab + 24 * B64, lane, aB);
          consume_q<6>(aA, 0,  wg0, wg1, wg2, wg3, acc);
          consume_q<6>(aB, 24, wg0, wg1, wg2, wg3, acc);
        }
      }
      #pragma unroll
      for (int c = 0; c < NCOL; ++c) zs[kq][c][lane] = acc[c];
    }
    __syncthreads();   // zs visible to pointwise

    // ---- pointwise phase ----
    if (threadIdx.x < UPB * B64) {
      const int uu = threadIdx.x >> 6;
      const int b  = lane;
      const int u  = u0 + uu;
      float z0 = bias[0 * U400 + u], z1 = bias[1 * U400 + u];
      float z2 = bias[2 * U400 + u], z3 = bias[3 * U400 + u];
      #pragma unroll
      for (int w = 0; w < NW; ++w) {
        z0 += zs[w][0 * UPB + uu][b];
        z1 += zs[w][1 * UPB + uu][b];
        z2 += zs[w][2 * UPB + uu][b];
        z3 += zs[w][3 * UPB + uu][b];
      }
      if (l == 0) {
        #pragma unroll
        for (int dd = 0; dd < 3; ++dd) {
          float xv = p.xT0[(t * 3 + dd) * B64 + b];
          z0 += xv * p.Wx0[dd * G1600 + 0 * U400 + u];
          z1 += xv * p.Wx0[dd * G1600 + 1 * U400 + u];
          z2 += xv * p.Wx0[dd * G1600 + 2 * U400 + u];
          z3 += xv * p.Wx0[dd * G1600 + 3 * U400 + u];
        }
      }
      float cp = creg;
      float ig = 1.f / (1.f + expf(-(z0 + pi[u] * cp)));
      float fg = 1.f / (1.f + expf(-(z1 + pf[u] * cp)));
      float gg = tanhf(z2);
      float cn = fg * cp + ig * gg;
      float og = 1.f / (1.f + expf(-(z3 + po[u] * cn)));
      creg = cn;
      float h = og * tanhf(cn);
      stg_c(&ownb[(size_t)(t & ownmask) * (U400 * B64) + (size_t)u * B64 + b], h);
    }

    // drain: every wave's s_waitcnt vmcnt(0) before s_barrier -> all coherent
    // h-stores acked at the coherence point before the arrive RMW below.
    __syncthreads();

    // ---- arrive (monotone accumulator; no resets) ----
    if (threadIdx.x == 0) {
      unsigned old = __hip_atomic_fetch_add(AAC(l), 1u, __ATOMIC_RELAXED,
                                            __HIP_MEMORY_SCOPE_AGENT);
      if (old == (unsigned)((t + 1) * NBPL - 1))
        __hip_atomic_store(CNT(l), (unsigned)(t + 1), __ATOMIC_RELAXED,
                           __HIP_MEMORY_SCOPE_AGENT);
    }
  }
}

// out[b][t][f] = bd[f] + sum_u h2[t][u][b] * Wd[u][f]
__launch_bounds__(256)
__global__ void dense_k(const float* __restrict__ h2, const float* __restrict__ Wd,
                        const float* __restrict__ bd, float* __restrict__ out) {
  int wid  = blockIdx.x * 4 + (threadIdx.x >> 6);
  int lane = threadIdx.x & 63;
  int t = wid / 3, f = wid - t * 3;
  if (t >= TT) return;
  float acc = bd[f];
  const float* hrow = h2 + (size_t)t * U400 * B64 + lane;
  #pragma unroll 4
  for (int u = 0; u < U400; ++u) acc += hrow[(size_t)u * B64] * Wd[u * 3 + f];
  out[((size_t)lane * TT + t) * 3 + f] = acc;
}

extern "C" void kernel_launch(void* const* d_in, const int* in_sizes, int n_in,
                              void* d_out, int out_size, void* d_ws, size_t ws_size,
                              hipStream_t stream) {
  const float* x   = (const float*)d_in[0];
  const float* Wx0 = (const float*)d_in[1];
  const float* Wh0 = (const float*)d_in[2];
  const float* pi0 = (const float*)d_in[3];
  const float* pf0 = (const float*)d_in[4];
  const float* po0 = (const float*)d_in[5];
  const float* b0  = (const float*)d_in[6];
  const float* Wx1 = (const float*)d_in[7];
  const float* Wh1 = (const float*)d_in[8];
  const float* pi1 = (const float*)d_in[9];
  const float* pf1 = (const float*)d_in[10];
  const float* po1 = (const float*)d_in[11];
  const float* b1  = (const float*)d_in[12];
  const float* Wx2 = (const float*)d_in[13];
  const float* Wh2 = (const float*)d_in[14];
  const float* pi2 = (const float*)d_in[15];
  const float* pf2 = (const float*)d_in[16];
  const float* po2 = (const float*)d_in[17];
  const float* b2  = (const float*)d_in[18];
  const float* Wd  = (const float*)d_in[19];
  const float* bd  = (const float*)d_in[20];

  float* ws   = (float*)d_ws;
  float* xT0  = ws;                  // 98304
  float* WhT0 = xT0  + 98304;        // 640000 each
  float* WhT1 = WhT0 + 640000;
  float* WhT2 = WhT1 + 640000;
  float* WxT1 = WhT2 + 640000;
  float* WxT2 = WxT1 + 640000;
  float* h0r  = WxT2 + 640000;       // 8*400*64 = 204800 each
  float* h1r  = h0r  + 204800;
  float* h2   = h1r  + 204800;       // 13107200
  unsigned* syn = (unsigned*)(h2 + 13107200);  // 6 lines x 128B

  hipMemsetAsync(syn, 0, 6 * 128, stream);

  hipLaunchKernelGGL(xpose_x_k, dim3(384), dim3(256), 0, stream, x, xT0);

  dim3 tb(32, 8);
  dim3 tg((G1600 + 31) / 32, (U400 + 31) / 32);
  hipLaunchKernelGGL(transpose_k, tg, tb, 0, stream, Wh0, WhT0, U400, G1600);
  hipLaunchKernelGGL(transpose_k, tg, tb, 0, stream, Wh1, WhT1, U400, G1600);
  hipLaunchKernelGGL(transpose_k, tg, tb, 0, stream, Wh2, WhT2, U400, G1600);
  hipLaunchKernelGGL(transpose_k, tg, tb, 0, stream, Wx1, WxT1, U400, G1600);
  hipLaunchKernelGGL(transpose_k, tg, tb, 0, stream, Wx2, WxT2, U400, G1600);

  ScanP hp;
  hp.xT0 = xT0;  hp.Wx0 = Wx0;
  hp.WxT1 = WxT1; hp.WxT2 = WxT2;
  hp.WhT0 = WhT0; hp.WhT1 = WhT1; hp.WhT2 = WhT2;
  hp.b0 = b0; hp.b1 = b1; hp.b2 = b2;
  hp.pi0 = pi0; hp.pi1 = pi1; hp.pi2 = pi2;
  hp.pf0 = pf0; hp.pf1 = pf1; hp.pf2 = pf2;
  hp.po0 = po0; hp.po1 = po1; hp.po2 = po2;
  hp.h0r = h0r; hp.h1r = h1r; hp.h2 = h2;
  hp.syn = syn;

  void* args[] = { &hp };
  hipLaunchCooperativeKernel((void*)lstm_scan_k, dim3(NBLK), dim3(NTHR),
                             args, 0, stream);

  hipLaunchKernelGGL(dense_k, dim3(384), dim3(256), 0, stream, h2, Wd, bd,
                     (float*)d_out);
}

// Round 12
// 19611.137 us; speedup vs baseline: 2.9356x; 1.7606x over previous
//
#include <hip/hip_runtime.h>
#include <math.h>

#define B64   64
#define TT    512
#define U400  400
#define G1600 1600
#define NBPL  80            // blocks per layer
#define UPB   5             // units per block (20 gate-columns)
#define NCOL  (4 * UPB)
#define NW    8             // waves per block
#define NTHR  512
#define NBLK  (3 * NBPL)    // 240 blocks -> 1/CU

// ---- device-coherent access helpers: bypass L1/L2, served at coherence point ----
__device__ __forceinline__ float ldg_c(const float* p) {
  return __hip_atomic_load(p, __ATOMIC_RELAXED, __HIP_MEMORY_SCOPE_AGENT);
}
__device__ __forceinline__ void stg_c(float* p, float v) {
  __hip_atomic_store(p, v, __ATOMIC_RELAXED, __HIP_MEMORY_SCOPE_AGENT);
}
__device__ __forceinline__ int adl(const unsigned* p) {
  return (int)__hip_atomic_load(p, __ATOMIC_RELAXED, __HIP_MEMORY_SCOPE_AGENT);
}

// x [64][512][3] -> xT [512][3][64]
__global__ void xpose_x_k(const float* __restrict__ x, float* __restrict__ xT) {
  int idx = blockIdx.x * 256 + threadIdx.x;
  if (idx < B64 * TT * 3) {
    int d = idx % 3;
    int t = (idx / 3) % TT;
    int b = idx / (3 * TT);
    xT[(t * 3 + d) * B64 + b] = x[idx];
  }
}

// generic tiled transpose: in R x C -> out C x R
__global__ void transpose_k(const float* __restrict__ in, float* __restrict__ out,
                            int R, int C) {
  __shared__ float tile[32][33];
  int bx = blockIdx.x * 32, by = blockIdx.y * 32;
  int tx = threadIdx.x, ty = threadIdx.y; // block (32,8)
  #pragma unroll
  for (int i = ty; i < 32; i += 8) {
    int r = by + i, c = bx + tx;
    if (r < R && c < C) tile[i][tx] = in[(size_t)r * C + c];
  }
  __syncthreads();
  #pragma unroll
  for (int i = ty; i < 32; i += 8) {
    int r = bx + i, c = by + tx;
    if (r < C && c < R) out[(size_t)r * R + c] = tile[tx][i];
  }
}

// ---- a-load pipeline pieces. Buffers are 10 floats (compile-time indices
// only -> VGPRs). Weights stay SCALAR reads off wave-uniform pointers
// (s_load -> SGPRs, zero VGPR pressure) exactly like the proven r4 codegen.
__device__ __forceinline__ void issue10(const float* __restrict__ base, int lane,
                                        float (&buf)[10]) {
  #pragma unroll
  for (int i = 0; i < 10; ++i)
    buf[i] = ldg_c(base + (size_t)i * B64 + lane);
}

__device__ __forceinline__ void cons10(const float (&buf)[10], int koff,
                                       const float* const (&wrow)[NCOL],
                                       float (&acc)[NCOL]) {
  #pragma unroll
  for (int i = 0; i < 10; ++i) {
    const float a = buf[i];
    #pragma unroll
    for (int c = 0; c < NCOL; ++c) acc[c] += a * wrow[c][koff + i];
  }
}

// K-slice of 100: 10 chunks, 2-stage alternating buffers (10-20 in flight)
__device__ __forceinline__ void gemm100(const float* __restrict__ aslab, int lane,
                                        const float* const (&wrow)[NCOL],
                                        float (&acc)[NCOL]) {
  float aA[10], aB[10];
  issue10(aslab +  0 * B64, lane, aA);
  issue10(aslab + 10 * B64, lane, aB);
  cons10(aA,  0, wrow, acc); issue10(aslab + 20 * B64, lane, aA);
  cons10(aB, 10, wrow, acc); issue10(aslab + 30 * B64, lane, aB);
  cons10(aA, 20, wrow, acc); issue10(aslab + 40 * B64, lane, aA);
  cons10(aB, 30, wrow, acc); issue10(aslab + 50 * B64, lane, aB);
  cons10(aA, 40, wrow, acc); issue10(aslab + 60 * B64, lane, aA);
  cons10(aB, 50, wrow, acc); issue10(aslab + 70 * B64, lane, aB);
  cons10(aA, 60, wrow, acc); issue10(aslab + 80 * B64, lane, aA);
  cons10(aB, 70, wrow, acc); issue10(aslab + 90 * B64, lane, aB);
  cons10(aA, 80, wrow, acc);
  cons10(aB, 90, wrow, acc);
}

// K-slice of 50: 5 chunks
__device__ __forceinline__ void gemm50(const float* __restrict__ aslab, int lane,
                                       const float* const (&wrow)[NCOL],
                                       float (&acc)[NCOL]) {
  float aA[10], aB[10];
  issue10(aslab +  0 * B64, lane, aA);
  issue10(aslab + 10 * B64, lane, aB);
  cons10(aA,  0, wrow, acc); issue10(aslab + 20 * B64, lane, aA);
  cons10(aB, 10, wrow, acc); issue10(aslab + 30 * B64, lane, aB);
  cons10(aA, 20, wrow, acc); issue10(aslab + 40 * B64, lane, aA);
  cons10(aB, 30, wrow, acc);
  cons10(aA, 40, wrow, acc);
}

struct ScanP {
  const float *xT0, *Wx0;
  const float *WxT1, *WxT2;
  const float *WhT0, *WhT1, *WhT2;
  const float *b0, *b1, *b2;
  const float *pi0, *pi1, *pi2;
  const float *pf0, *pf1, *pf2;
  const float *po0, *po1, *po2;
  float *h0r, *h1r;   // 8-slot h rings [8][400][64]
  float *h2;          // full [512][400][64]
  unsigned *syn;      // counters, 128B-strided
};

#define CNT(l)    (p.syn + (l) * 32)              // published step count, layer l
#define ROOT(l)   (p.syn + (3 + (l)) * 32)        // root arrive accumulator
#define GRP(l, g) (p.syn + (6 + (l) * 8 + (g)) * 32)  // 8 group accumulators/layer

// Persistent LSTM scan (round-4 proven skeleton + pipelined a-loads +
// two-level arrive tree). grid = 240 (80/layer), block = 512 (8 waves).
// l=0: waves split own-h K=400 as 8x50. l>0: waves 0-3 Wx (prev h, 4x100),
// waves 4-7 Wh (own h, 4x100). Weights scalar (SGPR), activations sc1.
__launch_bounds__(NTHR, 1)
__global__ void lstm_scan_k(ScanP p) {
  const int l    = blockIdx.x / NBPL;
  const int u0   = (blockIdx.x % NBPL) * UPB;
  const int grp  = (blockIdx.x % NBPL) / 10;     // arrive group 0..7
  const int lane = threadIdx.x & 63;
  const int kq   = __builtin_amdgcn_readfirstlane(threadIdx.x >> 6); // 0..7

  __shared__ float zs[NW][NCOL][B64];   // 40 KB partials

  const float* WhT  = (l == 0) ? p.WhT0 : (l == 1 ? p.WhT1 : p.WhT2);
  const float* WxT  = (l == 1) ? p.WxT1 : p.WxT2;      // unused for l==0
  const float* bias = (l == 0) ? p.b0  : (l == 1 ? p.b1  : p.b2);
  const float* pi   = (l == 0) ? p.pi0 : (l == 1 ? p.pi1 : p.pi2);
  const float* pf   = (l == 0) ? p.pf0 : (l == 1 ? p.pf1 : p.pf2);
  const float* po   = (l == 0) ? p.po0 : (l == 1 ? p.po1 : p.po2);
  const float* prevb = (l == 1) ? p.h0r : p.h1r;
  float* ownb = (l == 0) ? p.h0r : (l == 1 ? p.h1r : p.h2);
  const int ownmask = (l == 2) ? (TT - 1) : 7;

  // wave's K-slice (wave-uniform)
  const float* wb; int k0, isH;
  if (l == 0)      { wb = WhT; k0 = kq * 50;        isH = 1; }
  else if (kq < 4) { wb = WxT; k0 = kq * 100;       isH = 0; }
  else             { wb = WhT; k0 = (kq - 4) * 100; isH = 1; }

  const float* wrow[NCOL];
  #pragma unroll
  for (int g = 0; g < 4; ++g)
    #pragma unroll
    for (int uu = 0; uu < UPB; ++uu)
      wrow[g * UPB + uu] = wb + (size_t)(g * U400 + u0 + uu) * U400 + k0;

  float creg = 0.f;

  for (int t = 0; t < TT; ++t) {
    // ---- wait phase (thread 0 spins on device-coherent counters) ----
    if (threadIdx.x == 0) {
      while (adl(CNT(l)) < t) __builtin_amdgcn_s_sleep(4);
      if (l > 0)
        while (adl(CNT(l - 1)) < t + 1) __builtin_amdgcn_s_sleep(4);
      if (l < 2)
        while (adl(CNT(l + 1)) < t - 7) __builtin_amdgcn_s_sleep(4);
    }
    __syncthreads();

    // ---- GEMM phase: pipelined chunks, weights via SGPR scalar stream ----
    {
      float acc[NCOL];
      #pragma unroll
      for (int c = 0; c < NCOL; ++c) acc[c] = 0.f;

      if (!(isH && t == 0)) {
        const float* aslab = isH
            ? ownb  + (size_t)((t - 1) & ownmask) * (U400 * B64) + (size_t)k0 * B64
            : prevb + (size_t)(t & 7)             * (U400 * B64) + (size_t)k0 * B64;
        if (l == 0) gemm50(aslab, lane, wrow, acc);
        else        gemm100(aslab, lane, wrow, acc);
      }
      #pragma unroll
      for (int c = 0; c < NCOL; ++c) zs[kq][c][lane] = acc[c];
    }
    __syncthreads();   // zs visible to pointwise

    // ---- pointwise phase ----
    if (threadIdx.x < UPB * B64) {
      const int uu = threadIdx.x >> 6;
      const int b  = lane;
      const int u  = u0 + uu;
      float z0 = bias[0 * U400 + u], z1 = bias[1 * U400 + u];
      float z2 = bias[2 * U400 + u], z3 = bias[3 * U400 + u];
      #pragma unroll
      for (int w = 0; w < NW; ++w) {
        z0 += zs[w][0 * UPB + uu][b];
        z1 += zs[w][1 * UPB + uu][b];
        z2 += zs[w][2 * UPB + uu][b];
        z3 += zs[w][3 * UPB + uu][b];
      }
      if (l == 0) {
        #pragma unroll
        for (int dd = 0; dd < 3; ++dd) {
          float xv = p.xT0[(t * 3 + dd) * B64 + b];
          z0 += xv * p.Wx0[dd * G1600 + 0 * U400 + u];
          z1 += xv * p.Wx0[dd * G1600 + 1 * U400 + u];
          z2 += xv * p.Wx0[dd * G1600 + 2 * U400 + u];
          z3 += xv * p.Wx0[dd * G1600 + 3 * U400 + u];
        }
      }
      float cp = creg;
      float ig = 1.f / (1.f + expf(-(z0 + pi[u] * cp)));
      float fg = 1.f / (1.f + expf(-(z1 + pf[u] * cp)));
      float gg = tanhf(z2);
      float cn = fg * cp + ig * gg;
      float og = 1.f / (1.f + expf(-(z3 + po[u] * cn)));
      creg = cn;
      float h = og * tanhf(cn);
      stg_c(&ownb[(size_t)(t & ownmask) * (U400 * B64) + (size_t)u * B64 + b], h);
    }

    // drain: every wave's s_waitcnt vmcnt(0) before s_barrier -> all coherent
    // h-stores acked at the coherence point before the arrive RMW below.
    __syncthreads();

    // ---- two-level arrive tree (monotone accumulators; no resets) ----
    if (threadIdx.x == 0) {
      unsigned go = __hip_atomic_fetch_add(GRP(l, grp), 1u, __ATOMIC_RELAXED,
                                           __HIP_MEMORY_SCOPE_AGENT);
      if (go == (unsigned)((t + 1) * 10 - 1)) {       // last of 10 in group
        unsigned ro = __hip_atomic_fetch_add(ROOT(l), 1u, __ATOMIC_RELAXED,
                                             __HIP_MEMORY_SCOPE_AGENT);
        if (ro == (unsigned)((t + 1) * 8 - 1))        // last group of 8
          __hip_atomic_store(CNT(l), (unsigned)(t + 1), __ATOMIC_RELAXED,
                             __HIP_MEMORY_SCOPE_AGENT);
      }
    }
  }
}

// out[b][t][f] = bd[f] + sum_u h2[t][u][b] * Wd[u][f]
__launch_bounds__(256)
__global__ void dense_k(const float* __restrict__ h2, const float* __restrict__ Wd,
                        const float* __restrict__ bd, float* __restrict__ out) {
  int wid  = blockIdx.x * 4 + (threadIdx.x >> 6);
  int lane = threadIdx.x & 63;
  int t = wid / 3, f = wid - t * 3;
  if (t >= TT) return;
  float acc = bd[f];
  const float* hrow = h2 + (size_t)t * U400 * B64 + lane;
  #pragma unroll 4
  for (int u = 0; u < U400; ++u) acc += hrow[(size_t)u * B64] * Wd[u * 3 + f];
  out[((size_t)lane * TT + t) * 3 + f] = acc;
}

extern "C" void kernel_launch(void* const* d_in, const int* in_sizes, int n_in,
                              void* d_out, int out_size, void* d_ws, size_t ws_size,
                              hipStream_t stream) {
  const float* x   = (const float*)d_in[0];
  const float* Wx0 = (const float*)d_in[1];
  const float* Wh0 = (const float*)d_in[2];
  const float* pi0 = (const float*)d_in[3];
  const float* pf0 = (const float*)d_in[4];
  const float* po0 = (const float*)d_in[5];
  const float* b0  = (const float*)d_in[6];
  const float* Wx1 = (const float*)d_in[7];
  const float* Wh1 = (const float*)d_in[8];
  const float* pi1 = (const float*)d_in[9];
  const float* pf1 = (const float*)d_in[10];
  const float* po1 = (const float*)d_in[11];
  const float* b1  = (const float*)d_in[12];
  const float* Wx2 = (const float*)d_in[13];
  const float* Wh2 = (const float*)d_in[14];
  const float* pi2 = (const float*)d_in[15];
  const float* pf2 = (const float*)d_in[16];
  const float* po2 = (const float*)d_in[17];
  const float* b2  = (const float*)d_in[18];
  const float* Wd  = (const float*)d_in[19];
  const float* bd  = (const float*)d_in[20];

  float* ws   = (float*)d_ws;
  float* xT0  = ws;                  // 98304
  float* WhT0 = xT0  + 98304;        // 640000 each
  float* WhT1 = WhT0 + 640000;
  float* WhT2 = WhT1 + 640000;
  float* WxT1 = WhT2 + 640000;
  float* WxT2 = WxT1 + 640000;
  float* h0r  = WxT2 + 640000;       // 8*400*64 = 204800 each
  float* h1r  = h0r  + 204800;
  float* h2   = h1r  + 204800;       // 13107200
  unsigned* syn = (unsigned*)(h2 + 13107200);  // 30 lines x 128B

  hipMemsetAsync(syn, 0, 30 * 128, stream);

  hipLaunchKernelGGL(xpose_x_k, dim3(384), dim3(256), 0, stream, x, xT0);

  dim3 tb(32, 8);
  dim3 tg((G1600 + 31) / 32, (U400 + 31) / 32);
  hipLaunchKernelGGL(transpose_k, tg, tb, 0, stream, Wh0, WhT0, U400, G1600);
  hipLaunchKernelGGL(transpose_k, tg, tb, 0, stream, Wh1, WhT1, U400, G1600);
  hipLaunchKernelGGL(transpose_k, tg, tb, 0, stream, Wh2, WhT2, U400, G1600);
  hipLaunchKernelGGL(transpose_k, tg, tb, 0, stream, Wx1, WxT1, U400, G1600);
  hipLaunchKernelGGL(transpose_k, tg, tb, 0, stream, Wx2, WxT2, U400, G1600);

  ScanP hp;
  hp.xT0 = xT0;  hp.Wx0 = Wx0;
  hp.WxT1 = WxT1; hp.WxT2 = WxT2;
  hp.WhT0 = WhT0; hp.WhT1 = WhT1; hp.WhT2 = WhT2;
  hp.b0 = b0; hp.b1 = b1; hp.b2 = b2;
  hp.pi0 = pi0; hp.pi1 = pi1; hp.pi2 = pi2;
  hp.pf0 = pf0; hp.pf1 = pf1; hp.pf2 = pf2;
  hp.po0 = po0; hp.po1 = po1; hp.po2 = po2;
  hp.h0r = h0r; hp.h1r = h1r; hp.h2 = h2;
  hp.syn = syn;

  void* args[] = { &hp };
  hipLaunchCooperativeKernel((void*)lstm_scan_k, dim3(NBLK), dim3(NTHR),
                             args, 0, stream);

  hipLaunchKernelGGL(dense_k, dim3(384), dim3(256), 0, stream, h2, Wd, bd,
                     (float*)d_out);
}